// Round 8
// baseline (308.799 us; speedup 1.0000x reference)
//
#include <hip/hip_runtime.h>
#include <hip/hip_bf16.h>
#include <stdint.h>

// BERT self-attention fwd: B=4,S=2048,H=1024,NH=16,HD=64. fp32 in/out, bf16 MFMA compute.
// ws layout: Xb bf16[8192][1024] @0 (16MB) | Wt bf16[3072][1024] @16MB (6MB)
//            Qb bf16[64][2048][64] @22MB (Q pre-scaled by log2e/8) | Kb @38MB | Vt bf16[64][64][2048] @54MB

typedef unsigned short ushort_t;
typedef __attribute__((ext_vector_type(4))) float f32x4;
typedef __attribute__((ext_vector_type(16))) float f32x16;
typedef __attribute__((ext_vector_type(8))) short short8;

#define MFMA16(a, b, c) __builtin_amdgcn_mfma_f32_16x16x32_bf16((a), (b), (c), 0, 0, 0)
#define MFMA32(a, b, c) __builtin_amdgcn_mfma_f32_32x32x16_bf16((a), (b), (c), 0, 0, 0)

__device__ __forceinline__ ushort_t f2bf(float f) {
  unsigned u = __float_as_uint(f);
  u = (u + 0x7FFFu + ((u >> 16) & 1u)) >> 16;
  return (ushort_t)u;
}

typedef __attribute__((address_space(1))) unsigned int as1_uint;
typedef __attribute__((address_space(3))) unsigned int as3_uint;

// async global->LDS, 16B per lane; lds_dst wave-uniform base (lane writes base + lane*16)
__device__ __forceinline__ void async16(void* lds_dst, const void* g_src) {
  __builtin_amdgcn_global_load_lds((as1_uint*)(uintptr_t)g_src,
                                   (as3_uint*)(unsigned)(uintptr_t)lds_dst, 16, 0, 0);
}

// ---------------- convert X fp32 -> bf16 ----------------
__global__ __launch_bounds__(256) void convert_x(const float* __restrict__ X,
                                                 ushort_t* __restrict__ Xb) {
  int idx = (blockIdx.x * 256 + threadIdx.x) * 8;
  f32x4 a = *(const f32x4*)(X + idx);
  f32x4 b = *(const f32x4*)(X + idx + 4);
  short8 r;
#pragma unroll
  for (int j = 0; j < 4; ++j) r[j] = (short)f2bf(a[j]);
#pragma unroll
  for (int j = 0; j < 4; ++j) r[4 + j] = (short)f2bf(b[j]);
  *(short8*)(Xb + idx) = r;
}

// ---------------- convert + transpose W -> Wt[n][k] bf16, 3 mats stacked ----------------
__global__ __launch_bounds__(256) void convert_w(const float* __restrict__ Wq,
                                                 const float* __restrict__ Wk,
                                                 const float* __restrict__ Wv,
                                                 ushort_t* __restrict__ Wt) {
  const int mat = blockIdx.z;
  const float* W = (mat == 0) ? Wq : ((mat == 1) ? Wk : Wv);
  const int k0 = blockIdx.x * 64, n0 = blockIdx.y * 64;
  __shared__ float t[64][65];
  const int tid = threadIdx.x;
#pragma unroll
  for (int it = 0; it < 16; ++it) {
    int idx = it * 256 + tid;
    int r = idx >> 6, c = idx & 63;
    t[r][c] = W[(size_t)(k0 + r) * 1024 + n0 + c];
  }
  __syncthreads();
#pragma unroll
  for (int it = 0; it < 16; ++it) {
    int idx = it * 256 + tid;
    int nr = idx >> 6, kc = idx & 63;
    Wt[(size_t)(mat * 1024 + n0 + nr) * 1024 + k0 + kc] = f2bf(t[kc][nr]);
  }
}

// ---------------- fused QKV GEMM, 256x256 tile, 8 waves, 4-phase/K-tile counted-vmcnt ----------------
// grid (32, 12) x 512 thr. C[8192][3072] = Xb @ Wt^T; epilogue scatters to Qb/Kb/Vt.
// LDS 128KB: slot s (s=0,1) @ s*64KB: A 256x128B @0, B 256x128B @32KB.
// Window j computes K-tile j from slot j&1. Stages (per wave, 2 async16 each):
//   P1: Ah1(T_{j+1})->slot^1, P2: Bh0(T_{j+1}), P3: Bh1(T_{j+1}), P4: Ah0(T_{j+2})->slot (readless phase).
// vmcnt(1) at P4 (only Ah0(T_{j+2}) in flight) => T_{j+1} fully landed at window boundary.
__global__ __launch_bounds__(512, 2) void gemm_qkv(const ushort_t* __restrict__ Xb,
                                                   const ushort_t* __restrict__ Wt,
                                                   const float* __restrict__ bq,
                                                   const float* __restrict__ bk,
                                                   const float* __restrict__ bv,
                                                   ushort_t* __restrict__ Qb,
                                                   ushort_t* __restrict__ Kb,
                                                   ushort_t* __restrict__ Vt) {
  __shared__ __align__(16) char lds[131072];
  const int tid = threadIdx.x;
  const int l = tid & 63, w = tid >> 6;
  const int wm = w >> 2, wn = w & 3;  // 2 M-waves x 4 N-waves
  const int m0 = blockIdx.x * 256;
  const int n0 = blockIdx.y * 256;
  const int l15 = l & 15, lg4 = l >> 4;
  const int sw = (l & 7) << 4;

  // staging: lane covers phys slot (l&7), row (l>>3); inverse-swizzled source col
  const int colb = (((l & 7) ^ (l >> 3)) << 4);
  const char* srcA = (const char*)Xb + (size_t)(m0 + w * 16 + (l >> 3)) * 2048 + colb;
  const char* srcB = (const char*)Wt + (size_t)(n0 + w * 16 + (l >> 3)) * 2048 + colb;
  const int wrow = w * 16;  // wave's 16-row slice within each 128-row half-tile

#define STAGE(dst_base, src_base, h, t)                                     \
  do {                                                                      \
    const char* _g = (src_base) + (size_t)((h) * 128) * 2048 + (size_t)(t) * 128; \
    char* _d = (dst_base) + (h) * 16384 + wrow * 128;                       \
    async16(_d, _g);                                                        \
    async16(_d + 1024, _g + 8 * 2048);                                      \
  } while (0)

  f32x4 acc[8][4];
#pragma unroll
  for (int mf = 0; mf < 8; ++mf)
#pragma unroll
    for (int nf = 0; nf < 4; ++nf) acc[mf][nf] = (f32x4){0.f, 0.f, 0.f, 0.f};

  // prologue: T0 all 4 half-tiles -> slot0, Ah0(T1) -> slot1
  STAGE(lds, srcA, 0, 0);
  STAGE(lds, srcA, 1, 0);
  STAGE(lds + 32768, srcB, 0, 0);
  STAGE(lds + 32768, srcB, 1, 0);
  STAGE(lds + 65536, srcA, 0, 1);
  asm volatile("s_waitcnt vmcnt(2)" ::: "memory");
  __builtin_amdgcn_s_barrier();
  __builtin_amdgcn_sched_barrier(0);

  short8 av[4][2], bv4[4][2];

#pragma unroll 1
  for (int j = 0; j < 16; ++j) {
    const char* sp = lds + (j & 1) * 65536;
    char* os = lds + ((j & 1) ^ 1) * 65536;
    char* cs = lds + (j & 1) * 65536;

    // ---- P1: read A mf0-3 + B nf0-1; stage Ah1(T_{j+1}) ----
#pragma unroll
    for (int mf = 0; mf < 4; ++mf)
#pragma unroll
      for (int kh = 0; kh < 2; ++kh)
        av[mf][kh] = *(const short8*)(sp + (wm * 128 + mf * 16 + l15) * 128 +
                                      (((kh * 4 + lg4) << 4) ^ sw));
#pragma unroll
    for (int nf = 0; nf < 2; ++nf)
#pragma unroll
      for (int kh = 0; kh < 2; ++kh)
        bv4[nf][kh] = *(const short8*)(sp + 32768 + (wn * 64 + nf * 16 + l15) * 128 +
                                       (((kh * 4 + lg4) << 4) ^ sw));
    if (j < 15) STAGE(os, srcA, 1, j + 1);
    __builtin_amdgcn_s_barrier();
    asm volatile("s_waitcnt lgkmcnt(0)" ::: "memory");
    __builtin_amdgcn_sched_barrier(0);
    __builtin_amdgcn_s_setprio(1);
#pragma unroll
    for (int mf = 0; mf < 4; ++mf)
#pragma unroll
      for (int nf = 0; nf < 2; ++nf) {
        acc[mf][nf] = MFMA16(av[mf][0], bv4[nf][0], acc[mf][nf]);
        acc[mf][nf] = MFMA16(av[mf][1], bv4[nf][1], acc[mf][nf]);
      }
    __builtin_amdgcn_s_setprio(0);
    __builtin_amdgcn_s_barrier();

    // ---- P2: read B nf2-3; stage Bh0(T_{j+1}) ----
#pragma unroll
    for (int nf = 0; nf < 2; ++nf)
#pragma unroll
      for (int kh = 0; kh < 2; ++kh)
        bv4[2 + nf][kh] = *(const short8*)(sp + 32768 + (wn * 64 + (2 + nf) * 16 + l15) * 128 +
                                           (((kh * 4 + lg4) << 4) ^ sw));
    if (j < 15) STAGE(os + 32768, srcB, 0, j + 1);
    __builtin_amdgcn_s_barrier();
    asm volatile("s_waitcnt lgkmcnt(0)" ::: "memory");
    __builtin_amdgcn_sched_barrier(0);
    __builtin_amdgcn_s_setprio(1);
#pragma unroll
    for (int mf = 0; mf < 4; ++mf)
#pragma unroll
      for (int nf = 2; nf < 4; ++nf) {
        acc[mf][nf] = MFMA16(av[mf][0], bv4[nf][0], acc[mf][nf]);
        acc[mf][nf] = MFMA16(av[mf][1], bv4[nf][1], acc[mf][nf]);
      }
    __builtin_amdgcn_s_setprio(0);
    __builtin_amdgcn_s_barrier();

    // ---- P3: read A mf4-7; stage Bh1(T_{j+1}) ----
#pragma unroll
    for (int mf = 0; mf < 4; ++mf)
#pragma unroll
      for (int kh = 0; kh < 2; ++kh)
        av[mf][kh] = *(const short8*)(sp + (wm * 128 + (4 + mf) * 16 + l15) * 128 +
                                      (((kh * 4 + lg4) << 4) ^ sw));
    if (j < 15) STAGE(os + 32768, srcB, 1, j + 1);
    __builtin_amdgcn_s_barrier();
    asm volatile("s_waitcnt lgkmcnt(0)" ::: "memory");
    __builtin_amdgcn_sched_barrier(0);
    __builtin_amdgcn_s_setprio(1);
#pragma unroll
    for (int mf = 0; mf < 4; ++mf)
#pragma unroll
      for (int nf = 2; nf < 4; ++nf) {
        acc[4 + mf][nf] = MFMA16(av[mf][0], bv4[nf][0], acc[4 + mf][nf]);
        acc[4 + mf][nf] = MFMA16(av[mf][1], bv4[nf][1], acc[4 + mf][nf]);
      }
    __builtin_amdgcn_s_setprio(0);
    __builtin_amdgcn_s_barrier();

    // ---- P4 (readless): stage Ah0(T_{j+2}) into CURRENT slot; counted vmcnt ----
    if (j < 14) {
      STAGE(cs, srcA, 0, j + 2);
      asm volatile("s_waitcnt vmcnt(1)" ::: "memory");
    } else if (j == 14) {
      asm volatile("s_waitcnt vmcnt(0)" ::: "memory");
    }
    __builtin_amdgcn_s_barrier();
    __builtin_amdgcn_sched_barrier(0);
    __builtin_amdgcn_s_setprio(1);
#pragma unroll
    for (int mf = 0; mf < 4; ++mf)
#pragma unroll
      for (int nf = 0; nf < 2; ++nf) {
        acc[4 + mf][nf] = MFMA16(av[mf][0], bv4[nf][0], acc[4 + mf][nf]);
        acc[4 + mf][nf] = MFMA16(av[mf][1], bv4[nf][1], acc[4 + mf][nf]);
      }
    __builtin_amdgcn_s_setprio(0);
    __builtin_amdgcn_s_barrier();
  }
#undef STAGE

  // ---------------- epilogue ----------------
  const int col0 = n0 + wn * 64;
  const int mat = col0 >> 10;
  const int nn0 = col0 & 1023;
  const int hh = nn0 >> 6;
  const int row0 = m0 + wm * 128;
  const int bb = row0 >> 11;
  const int s0 = row0 & 2047;
  const float* bias = (mat == 0) ? bq : ((mat == 1) ? bk : bv);
  const float qscale = 0.18033688011112042f;  // log2(e)/sqrt(64), folded into Q
  if (mat < 2) {
    ushort_t* dst = (mat == 0) ? Qb : Kb;
    const float scl = (mat == 0) ? qscale : 1.0f;
#pragma unroll
    for (int mf = 0; mf < 8; ++mf)
#pragma unroll
      for (int nf = 0; nf < 4; ++nf)
#pragma unroll
        for (int i = 0; i < 4; ++i) {
          int r = mf * 16 + lg4 * 4 + i;
          int d = nf * 16 + l15;
          float v = (acc[mf][nf][i] + bias[nn0 + d]) * scl;
          dst[((size_t)(bb * 16 + hh) * 2048 + (s0 + r)) * 64 + d] = f2bf(v);
        }
  } else {
    // V: two 64-row passes; per-wave private LDS region (stride 72 u16 = 144B, b128-aligned)
    ushort_t* vw = (ushort_t*)(lds + w * 9216);
#pragma unroll 1
    for (int rh = 0; rh < 2; ++rh) {
#pragma unroll
      for (int mf = 0; mf < 4; ++mf)
#pragma unroll
        for (int nf = 0; nf < 4; ++nf)
#pragma unroll
          for (int i = 0; i < 4; ++i) {
            int rl = mf * 16 + lg4 * 4 + i;
            int d = nf * 16 + l15;
            float v = acc[rh * 4 + mf][nf][i] + bias[nn0 + d];
            vw[d * 72 + rl] = f2bf(v);
          }
#pragma unroll
      for (int it = 0; it < 8; ++it) {
        int dr = it * 8 + (l >> 3);
        int sc = (l & 7) * 8;
        short8 vv = *(const short8*)((const char*)vw + dr * 144 + sc * 2);
        *(short8*)((char*)Vt + (((size_t)(bb * 16 + hh) * 64 + dr) * 2048 + s0 + rh * 64 + sc) * 2) = vv;
      }
    }
  }
}

// ---------------- flash attention fwd: 32x32 MFMA, in-register P via shfl_xor(32) ----------------
// grid (16, 64): x = q-tile (128 rows), y = b*16+h. 4 waves x 32 q-rows. KVBLK=64.
// LDS: klds 2x8KB @0 | vlds 2x8KB @16384 | sbuf 4x128B @32768
__global__ __launch_bounds__(256, 4) void attn_fwd(const ushort_t* __restrict__ Qb,
                                                   const ushort_t* __restrict__ Kb,
                                                   const ushort_t* __restrict__ Vt,
                                                   const float* __restrict__ mask,
                                                   float* __restrict__ out) {
  __shared__ char lds[33280];
  const int tid = threadIdx.x, l = tid & 63, w = tid >> 6;
  const int bh = blockIdx.y;
  const int bb = bh >> 4, hh = bh & 15;
  const int q0 = blockIdx.x * 128;
  const int l31 = l & 31, hi = l >> 5;
  char* klds = lds;
  char* vlds = lds + 16384;
  float* sbuf = (float*)(lds + 32768) + w * 32;

  const float LOG2E = 1.44269504088896340736f;
  const int psz = (l & 7) << 4;  // XOR swizzle; row&7 == l&7 for all read rows

  // Q B-frags (pre-scaled by log2e/8): col=q=l31, chunk c: k(d) = c*16 + hi*8 + j
  const char* qrow = (const char*)Qb + ((size_t)bh * 2048 + q0 + w * 32 + l31) * 128 + hi * 16;
  short8 qf[4];
#pragma unroll
  for (int c = 0; c < 4; ++c) qf[c] = *(const short8*)(qrow + c * 32);

  // staging sources (inverse-swizzled global col so linear LDS dest + swizzled reads agree)
  const int srow = l >> 3;
  const int scol = ((l & 7) ^ srow) << 4;
  const char* ksrc0 = (const char*)Kb + (size_t)bh * 2048 * 128 + (size_t)(w * 16 + srow) * 128 + scol;
  const char* vsrc0 = (const char*)Vt + ((size_t)bh * 64 + w * 16 + srow) * 4096 + scol;

  // prologue: stage tile 0 into buf 0
  {
    char* kd = klds + w * 2048;
    char* vd = vlds + w * 2048;
    async16(kd, ksrc0);
    async16(kd + 1024, ksrc0 + 1024);
    async16(vd, vsrc0);
    async16(vd + 1024, vsrc0 + 8 * 4096);
  }

  const float* mrow = mask + (size_t)bb * 2048;

  f32x16 o0, o1;
#pragma unroll
  for (int i = 0; i < 16; ++i) { o0[i] = 0.f; o1[i] = 0.f; }
  f32x4 lsum4 = (f32x4){0.f, 0.f, 0.f, 0.f};

#pragma unroll 1
  for (int kt = 0; kt < 32; ++kt) {
    const int cur = kt & 1;
    // everyone done reading buf[cur^1] -> safe to overwrite
    asm volatile("s_waitcnt lgkmcnt(0)" ::: "memory");
    __builtin_amdgcn_s_barrier();
    __builtin_amdgcn_sched_barrier(0);
    if (kt < 31) {
      char* kd = klds + (cur ^ 1) * 8192 + w * 2048;
      char* vd = vlds + (cur ^ 1) * 8192 + w * 2048;
      const char* ks = ksrc0 + (size_t)(kt + 1) * 8192;
      const char* vs = vsrc0 + (kt + 1) * 128;
      async16(kd, ks);
      async16(kd + 1024, ks + 1024);
      async16(vd, vs);
      async16(vd + 1024, vs + 8 * 4096);
      asm volatile("s_waitcnt vmcnt(4)" ::: "memory");  // tile kt landed; kt+1 in flight
    } else {
      asm volatile("s_waitcnt vmcnt(0)" ::: "memory");
    }
    __builtin_amdgcn_s_barrier();  // buf[cur] visible to all waves
    __builtin_amdgcn_sched_barrier(0);

    const char* kbuf = klds + cur * 8192;
    const char* vbuf = vlds + cur * 8192;

#pragma unroll
    for (int kb = 0; kb < 2; ++kb) {
      // QK^T swapped: A = K rows (key=l31 within kb block), B = Q (col=q=l31)
      // D[key][q]: q=l31, key_local = (reg&3) + 8*(reg>>2) + 4*hi
      f32x16 s;
#pragma unroll
      for (int i = 0; i < 16; ++i) s[i] = 0.f;
#pragma unroll
      for (int c = 0; c < 4; ++c) {
        short8 kf = *(const short8*)(kbuf + (kb * 32 + l31) * 128 + ((c * 32 + hi * 16) ^ psz));
        s = MFMA32(kf, qf[c], s);
      }
      // static-max softmax in log2 domain: p = exp2(s + mask*log2e)
      f32x16 pp;
#pragma unroll
      for (int r2 = 0; r2 < 4; ++r2) {
        f32x4 m4 = *(const f32x4*)(mrow + kt * 64 + kb * 32 + 8 * r2 + 4 * hi);
#pragma unroll
        for (int i = 0; i < 4; ++i)
          pp[4 * r2 + i] = __builtin_amdgcn_exp2f(fmaf(m4[i], LOG2E, s[4 * r2 + i]));
      }
#pragma unroll
      for (int i = 0; i < 4; ++i)
        lsum4[i] += ((pp[i] + pp[4 + i]) + (pp[8 + i] + pp[12 + i]));

      // P -> bf16 A-frags in-register.
      // u[2*r2+p] = pack(keys 8r2+4hi+2p, +1). pa[c] word w must hold keys 16c+8hi+2w,+1.
      // Cross-half exchange via shfl_xor(32): hi=0 sends u[4c+2{,+1}], hi=1 sends u[4c{,+1}].
      unsigned u[8];
#pragma unroll
      for (int r2 = 0; r2 < 4; ++r2) {
        asm("v_cvt_pk_bf16_f32 %0, %1, %2"
            : "=v"(u[2 * r2]) : "v"(pp[4 * r2]), "v"(pp[4 * r2 + 1]));
        asm("v_cvt_pk_bf16_f32 %0, %1, %2"
            : "=v"(u[2 * r2 + 1]) : "v"(pp[4 * r2 + 2]), "v"(pp[4 * r2 + 3]));
      }
      short8 pa[2];
#pragma unroll
      for (int c = 0; c < 2; ++c) {
        unsigned a0 = u[4 * c], b0 = u[4 * c + 2];
        unsigned a1 = u[4 * c + 1], b1 = u[4 * c + 3];
        unsigned s0 = hi ? a0 : b0;
        unsigned s1 = hi ? a1 : b1;
        unsigned r0 = (unsigned)__shfl_xor((int)s0, 32);
        unsigned r1 = (unsigned)__shfl_xor((int)s1, 32);
        union { unsigned uu[4]; short8 s8; } cv;
        cv.uu[0] = hi ? r0 : a0;  // word0: keys 16c+8hi+0,1
        cv.uu[1] = hi ? r1 : a1;  // word1: keys 16c+8hi+2,3
        cv.uu[2] = hi ? b0 : r0;  // word2: keys 16c+8hi+4,5
        cv.uu[3] = hi ? b1 : r1;  // word3: keys 16c+8hi+6,7
        pa[c] = cv.s8;
      }

      // PV for this key-block: A = P[q][key], B = V^T[d][key]; D col=d, row=q
      __builtin_amdgcn_s_setprio(1);
#pragma unroll
      for (int c = 0; c < 2; ++c) {
        const int koff = (kb * 64 + c * 32 + hi * 16) ^ psz;
        short8 v0 = *(const short8*)(vbuf + l31 * 128 + koff);
        short8 v1 = *(const short8*)(vbuf + (32 + l31) * 128 + koff);
        o0 = MFMA32(pa[c], v0, o0);
        o1 = MFMA32(pa[c], v1, o1);
      }
      __builtin_amdgcn_s_setprio(0);
    }
  }

  // epilogue: cross-half sum via shfl_xor(32), invert, redistribute to O layout
  float ls = (lsum4[0] + lsum4[1]) + (lsum4[2] + lsum4[3]);
  float other = __shfl_xor(ls, 32);
  float inv = 1.0f / (ls + other);
  if (hi == 0) sbuf[l31] = inv;
  float* obase = out + ((size_t)bb * 2048 + q0 + w * 32) * 1024 + hh * 64;
#pragma unroll
  for (int r2 = 0; r2 < 4; ++r2) {
    f32x4 iv = *(const f32x4*)(sbuf + 8 * r2 + 4 * hi);
#pragma unroll
    for (int r0 = 0; r0 < 4; ++r0) {
      const int q = 8 * r2 + 4 * hi + r0;
      obase[(size_t)q * 1024 + l31] = o0[4 * r2 + r0] * iv[r0];
      obase[(size_t)q * 1024 + 32 + l31] = o1[4 * r2 + r0] * iv[r0];
    }
  }
}

extern "C" void kernel_launch(void* const* d_in, const int* in_sizes, int n_in,
                              void* d_out, int out_size, void* d_ws, size_t ws_size,
                              hipStream_t stream) {
  const float* hs  = (const float*)d_in[0];
  const float* msk = (const float*)d_in[1];
  const float* Wq  = (const float*)d_in[2];
  const float* bq  = (const float*)d_in[3];
  const float* Wk  = (const float*)d_in[4];
  const float* bk  = (const float*)d_in[5];
  const float* Wv  = (const float*)d_in[6];
  const float* bv  = (const float*)d_in[7];
  float* out = (float*)d_out;
  char* ws = (char*)d_ws;
  ushort_t* Xb = (ushort_t*)ws;
  ushort_t* Wt = (ushort_t*)(ws + (16u << 20));
  ushort_t* Qb = (ushort_t*)(ws + (22u << 20));
  ushort_t* Kb = (ushort_t*)(ws + (38u << 20));
  ushort_t* Vt = (ushort_t*)(ws + (54u << 20));

  convert_x<<<4096, 256, 0, stream>>>(hs, Xb);
  convert_w<<<dim3(16, 16, 3), 256, 0, stream>>>(Wq, Wk, Wv, Wt);
  gemm_qkv<<<dim3(32, 12), 512, 0, stream>>>(Xb, Wt, bq, bk, bv, Qb, Kb, Vt);
  attn_fwd<<<dim3(16, 64), 256, 0, stream>>>(Qb, Kb, Vt, msk, out);
}